// Round 6
// baseline (14754.794 us; speedup 1.0000x reference)
//
#include <hip/hip_runtime.h>
#include <hip/hip_bf16.h>

#define B_ 8
#define T_ 16
#define S_ 257
#define D_ 512
#define FFN_ 2048
#define NH_ 8
#define HD_ 64
#define PTD_ 192
#define NTOK (B_*T_*S_)        // 32896
#define CH 4112                // 16 frames * 257 rows per chunk
#define MCH 3072               // MLP row chunk
#define WSCALE 64.0f
#define WINV 0.015625f

typedef unsigned int uint;
typedef unsigned short ushort;
typedef __attribute__((ext_vector_type(8))) _Float16 half8;
typedef __attribute__((ext_vector_type(4))) float f32x4;

__device__ __forceinline__ float warp_rsum(float v){
#pragma unroll
  for (int m = 32; m >= 1; m >>= 1) v += __shfl_xor(v, m);
  return v;
}
__device__ __forceinline__ float warp_rmax(float v){
#pragma unroll
  for (int m = 32; m >= 1; m >>= 1) v = fmaxf(v, __shfl_xor(v, m));
  return v;
}
__device__ __forceinline__ float gelu_f(float x){
  float x3 = x*x*x;
  return 0.5f*x*(1.0f + tanhf(0.7978845608028654f*(x + 0.044715f*x3)));
}
// split fp32 -> f16 hi + f16 lo (RNE).  x ~ hi + lo with ~2^-22 rel err (normal range).
__device__ __forceinline__ void split_f16(float f, ushort& h, ushort& l){
  _Float16 hh = (_Float16)f;
  float hf = (float)hh;
  _Float16 ll = (_Float16)(f - hf);
  h = __builtin_bit_cast(ushort, hh);
  l = __builtin_bit_cast(ushort, ll);
}

// ---------------- fused LN + f16-split:  aH/aL[row][512] = split(LN(x[row]))
__global__ __launch_bounds__(256) void ln_split(
    const float* __restrict__ x, const float* __restrict__ g,
    const float* __restrict__ bb, ushort* __restrict__ aH, ushort* __restrict__ aL)
{
  int row = blockIdx.x * 4 + (threadIdx.x >> 6);
  int lane = threadIdx.x & 63;
  const float* xr = x + (long)row * D_;
  float4 u0 = *(const float4*)(xr + lane * 8);
  float4 u1 = *(const float4*)(xr + lane * 8 + 4);
  float s = u0.x + u0.y + u0.z + u0.w + u1.x + u1.y + u1.z + u1.w;
  s = warp_rsum(s);
  float mean = s * (1.0f / 512.0f);
  float d[8] = {u0.x - mean, u0.y - mean, u0.z - mean, u0.w - mean,
                u1.x - mean, u1.y - mean, u1.z - mean, u1.w - mean};
  float ss = 0.f;
#pragma unroll
  for (int i = 0; i < 8; i++) ss = fmaf(d[i], d[i], ss);
  ss = warp_rsum(ss);
  float rstd = rsqrtf(ss * (1.0f / 512.0f) + 1e-5f);
  int c = lane * 8;
  float4 g0 = *(const float4*)(g + c), g1 = *(const float4*)(g + c + 4);
  float4 b0 = *(const float4*)(bb + c), b1 = *(const float4*)(bb + c + 4);
  float y[8] = {d[0]*rstd*g0.x + b0.x, d[1]*rstd*g0.y + b0.y,
                d[2]*rstd*g0.z + b0.z, d[3]*rstd*g0.w + b0.w,
                d[4]*rstd*g1.x + b1.x, d[5]*rstd*g1.y + b1.y,
                d[6]*rstd*g1.z + b1.z, d[7]*rstd*g1.w + b1.w};
  ushort h[8], l[8];
#pragma unroll
  for (int i = 0; i < 8; i++) split_f16(y[i], h[i], l[i]);
  uint4 hv = make_uint4((uint)h[0] | ((uint)h[1] << 16), (uint)h[2] | ((uint)h[3] << 16),
                        (uint)h[4] | ((uint)h[5] << 16), (uint)h[6] | ((uint)h[7] << 16));
  uint4 lv = make_uint4((uint)l[0] | ((uint)l[1] << 16), (uint)l[2] | ((uint)l[3] << 16),
                        (uint)l[4] | ((uint)l[5] << 16), (uint)l[6] | ((uint)l[7] << 16));
  *(uint4*)(aH + (long)row * 512 + c) = hv;
  *(uint4*)(aL + (long)row * 512 + c) = lv;
}

// ---------------- weight transpose + split:  W[K][N] f32 -> (W*64) as Whi[N][K], Wlo[N][K] f16
__global__ __launch_bounds__(256) void convert_w(
    const float* __restrict__ W, ushort* __restrict__ Whi, ushort* __restrict__ Wlo,
    int N, int K)
{
  __shared__ float Tt[64][65];
  const int tid = threadIdx.x;
  const int k0 = blockIdx.x << 6, n0 = blockIdx.y << 6;
  {
    int kk = tid >> 2, nb = (tid & 3) << 4;
#pragma unroll
    for (int q = 0; q < 4; q++) {
      float4 v = *(const float4*)(W + (long)(k0 + kk) * N + n0 + nb + 4 * q);
      Tt[kk][nb + 4*q + 0] = v.x; Tt[kk][nb + 4*q + 1] = v.y;
      Tt[kk][nb + 4*q + 2] = v.z; Tt[kk][nb + 4*q + 3] = v.w;
    }
  }
  __syncthreads();
  {
    int nn = tid >> 2, kb = (tid & 3) << 4;
    uint hw[8], lw[8];
#pragma unroll
    for (int q = 0; q < 8; q++) {
      float a = Tt[kb + 2*q][nn] * WSCALE, b = Tt[kb + 2*q + 1][nn] * WSCALE;
      ushort ha, la, hb, lb;
      split_f16(a, ha, la); split_f16(b, hb, lb);
      hw[q] = (uint)ha | ((uint)hb << 16); lw[q] = (uint)la | ((uint)lb << 16);
    }
    ushort* dh = Whi + (long)(n0 + nn) * K + k0 + kb;
    ushort* dl = Wlo + (long)(n0 + nn) * K + k0 + kb;
    ((uint4*)dh)[0] = make_uint4(hw[0], hw[1], hw[2], hw[3]);
    ((uint4*)dh)[1] = make_uint4(hw[4], hw[5], hw[6], hw[7]);
    ((uint4*)dl)[0] = make_uint4(lw[0], lw[1], lw[2], lw[3]);
    ((uint4*)dl)[1] = make_uint4(lw[4], lw[5], lw[6], lw[7]);
  }
}

// ---------------- split-f16 MFMA GEMM.  A pre-split (AMODE=0) or fused-patchify (AMODE=1).
// C[M][N] (=|+=) act((A @ Wt^T)/64 (+bias));  SOUT: write C as f16 hi/lo pair instead.
template<int BN, int TM, int TN, int AMODE, bool BIAS, bool GELU, bool RESID, bool SOUT>
__global__ __launch_bounds__(256) void gemm_mfma(
    const ushort* __restrict__ aHp, const ushort* __restrict__ aLp, int lda,
    const ushort* __restrict__ wtH, const ushort* __restrict__ wtL, int ldb,
    const float* __restrict__ bias, float* __restrict__ C,
    ushort* __restrict__ coH, ushort* __restrict__ coL,
    const float* __restrict__ videos, const float* __restrict__ atok,
    int M, int N, int K)
{
  constexpr int NWC = BN / (TN * 16);
  __shared__ __align__(16) ushort sAh[128 * 40];
  __shared__ __align__(16) ushort sAl[128 * 40];
  __shared__ __align__(16) ushort sBh[BN * 40];
  __shared__ __align__(16) ushort sBl[BN * 40];
  const int tid = threadIdx.x;
  const int m0 = blockIdx.x * 128, n0 = blockIdx.y * BN;
  const int wid = tid >> 6, lane = tid & 63;
  const int lrow = lane & 15, lkg = lane >> 4;
  const int wr = wid / NWC, wc = wid % NWC;
  const int wrb = wr * TM * 16, wcb = wc * TN * 16;
  f32x4 acc[TM][TN];
#pragma unroll
  for (int mi = 0; mi < TM; mi++)
#pragma unroll
    for (int ni = 0; ni < TN; ni++) acc[mi][ni] = (f32x4){0.f, 0.f, 0.f, 0.f};

  const int rowa = tid >> 1, kba = (tid & 1) << 4;
  const int arow = m0 + rowa;
  const bool rowok = (arow < M);
  int bt_p = 0, s_p = 0;
  if (AMODE == 1) { bt_p = arow / 257; s_p = arow - bt_p * 257; }

  for (int k0 = 0; k0 < K; k0 += 32) {
    // ---- stage A
    if (AMODE == 0) {
      uint4 h0 = make_uint4(0,0,0,0), h1 = h0, l0 = h0, l1 = h0;
      if (rowok) {
        const uint4* sh = (const uint4*)(aHp + (long)arow * lda + k0 + kba);
        const uint4* sl = (const uint4*)(aLp + (long)arow * lda + k0 + kba);
        h0 = sh[0]; h1 = sh[1]; l0 = sl[0]; l1 = sl[1];
      }
      uint4* dh = (uint4*)&sAh[rowa * 40 + kba];
      dh[0] = h0; dh[1] = h1;
      uint4* dl = (uint4*)&sAl[rowa * 40 + kba];
      dl[0] = l0; dl[1] = l1;
    } else {
      float4 vr[4];
#pragma unroll
      for (int q = 0; q < 4; q++) vr[q] = make_float4(0.f, 0.f, 0.f, 0.f);
#pragma unroll
      for (int q = 0; q < 4; q++) {
        int e4 = k0 + kba + 4 * q;
        if (s_p == 0) {
          vr[q] = *(const float4*)(atok + e4);
        } else {
          int p = s_p - 1, ph = p >> 4, pw = p & 15;
          int iq = e4 / 24, jc = e4 - iq * 24;
          vr[q] = *(const float4*)(videos + (long)bt_p * 49152 +
                                   (long)(ph * 8 + iq) * 384 + pw * 24 + jc);
        }
      }
      uint hw[8], lw[8];
#pragma unroll
      for (int q = 0; q < 4; q++) {
        ushort h0,l0,h1,l1,h2,l2,h3,l3;
        split_f16(vr[q].x, h0, l0); split_f16(vr[q].y, h1, l1);
        split_f16(vr[q].z, h2, l2); split_f16(vr[q].w, h3, l3);
        hw[2*q]   = (uint)h0 | ((uint)h1 << 16); lw[2*q]   = (uint)l0 | ((uint)l1 << 16);
        hw[2*q+1] = (uint)h2 | ((uint)h3 << 16); lw[2*q+1] = (uint)l2 | ((uint)l3 << 16);
      }
      uint4* dh = (uint4*)&sAh[rowa * 40 + kba];
      dh[0] = make_uint4(hw[0], hw[1], hw[2], hw[3]);
      dh[1] = make_uint4(hw[4], hw[5], hw[6], hw[7]);
      uint4* dl = (uint4*)&sAl[rowa * 40 + kba];
      dl[0] = make_uint4(lw[0], lw[1], lw[2], lw[3]);
      dl[1] = make_uint4(lw[4], lw[5], lw[6], lw[7]);
    }
    // ---- stage B (pre-split f16, straight copies)
    if (BN == 128) {
      const int colb = tid >> 1, kbb = (tid & 1) << 4;
      const ushort* srch = wtH + (long)(n0 + colb) * ldb + k0 + kbb;
      const ushort* srcl = wtL + (long)(n0 + colb) * ldb + k0 + kbb;
      uint4* dh = (uint4*)&sBh[colb * 40 + kbb];
      dh[0] = ((const uint4*)srch)[0]; dh[1] = ((const uint4*)srch)[1];
      uint4* dl = (uint4*)&sBl[colb * 40 + kbb];
      dl[0] = ((const uint4*)srcl)[0]; dl[1] = ((const uint4*)srcl)[1];
    } else {
      const int colb = tid >> 2, kbb = (tid & 3) << 3;
      *(uint4*)&sBh[colb * 40 + kbb] = *(const uint4*)(wtH + (long)(n0 + colb) * ldb + k0 + kbb);
      *(uint4*)&sBl[colb * 40 + kbb] = *(const uint4*)(wtL + (long)(n0 + colb) * ldb + k0 + kbb);
    }
    __syncthreads();
    // ---- compute: 3 MFMA per fragment pair (AhBh + AhBl + AlBh), fp32 accumulate
    half8 aH[TM], aL[TM];
#pragma unroll
    for (int mi = 0; mi < TM; mi++) {
      int off = (wrb + mi * 16 + lrow) * 40 + lkg * 8;
      aH[mi] = *(const half8*)&sAh[off];
      aL[mi] = *(const half8*)&sAl[off];
    }
#pragma unroll
    for (int ni = 0; ni < TN; ni++) {
      int off = (wcb + ni * 16 + lrow) * 40 + lkg * 8;
      half8 bH = *(const half8*)&sBh[off];
      half8 bL = *(const half8*)&sBl[off];
#pragma unroll
      for (int mi = 0; mi < TM; mi++) {
        acc[mi][ni] = __builtin_amdgcn_mfma_f32_16x16x32_f16(aL[mi], bH, acc[mi][ni], 0, 0, 0);
        acc[mi][ni] = __builtin_amdgcn_mfma_f32_16x16x32_f16(aH[mi], bL, acc[mi][ni], 0, 0, 0);
        acc[mi][ni] = __builtin_amdgcn_mfma_f32_16x16x32_f16(aH[mi], bH, acc[mi][ni], 0, 0, 0);
      }
    }
    __syncthreads();
  }
  // ---- epilogue (unscale by 1/64, then bias/act; store fp32 or split f16)
#pragma unroll
  for (int mi = 0; mi < TM; mi++) {
    int rowg = m0 + wrb + mi * 16 + lkg * 4;
#pragma unroll
    for (int j = 0; j < 4; j++) {
      int r = rowg + j;
      if (r < M) {
#pragma unroll
        for (int ni = 0; ni < TN; ni++) {
          int cg = n0 + wcb + ni * 16 + lrow;
          float v = acc[mi][ni][j] * WINV;
          if (BIAS) v += bias[cg];
          if (GELU) v = gelu_f(v);
          long idx = (long)r * N + cg;
          if (SOUT) {
            ushort h, l;
            split_f16(v, h, l);
            coH[idx] = h; coL[idx] = l;
          } else {
            if (RESID) C[idx] += v; else C[idx] = v;
          }
        }
      }
    }
  }
}

// ---------------- spatial attention (fp32): scores for 64 (frame,head) pairs of a chunk
__global__ __launch_bounds__(256) void spatial_scores(
    const float* __restrict__ qkvc, float* __restrict__ scores, int fh_base)
{
  const int fh = fh_base + blockIdx.z;
  const int fl = fh >> 3, hh = fh & 7;
  const float* Q  = qkvc + (long)fl * S_ * 1536 + hh * HD_;
  const float* Kp = Q + 512;
  float* Cm = scores + (long)blockIdx.z * S_ * S_;
  const int m0 = blockIdx.x << 6, n0 = blockIdx.y << 6;
  __shared__ __align__(16) float Qs[16][68];
  __shared__ __align__(16) float Ks[16][68];
  const int tid = threadIdx.x, tx = tid & 15, ty = tid >> 4;
  const int lr = tid >> 2, lc = (tid & 3) << 2;
  float acc[4][4] = {};
  for (int k0 = 0; k0 < 64; k0 += 16) {
    float4 qv = make_float4(0,0,0,0), kv = make_float4(0,0,0,0);
    if (m0 + lr < S_) qv = *(const float4*)(Q  + (long)(m0 + lr) * 1536 + k0 + lc);
    if (n0 + lr < S_) kv = *(const float4*)(Kp + (long)(n0 + lr) * 1536 + k0 + lc);
    Qs[lc+0][lr]=qv.x; Qs[lc+1][lr]=qv.y; Qs[lc+2][lr]=qv.z; Qs[lc+3][lr]=qv.w;
    Ks[lc+0][lr]=kv.x; Ks[lc+1][lr]=kv.y; Ks[lc+2][lr]=kv.z; Ks[lc+3][lr]=kv.w;
    __syncthreads();
#pragma unroll
    for (int kk = 0; kk < 16; kk++) {
      const float4 a4 = *(const float4*)&Qs[kk][ty << 2];
      const float4 b4 = *(const float4*)&Ks[kk][tx << 2];
      const float a_[4] = {a4.x, a4.y, a4.z, a4.w};
      const float b_[4] = {b4.x, b4.y, b4.z, b4.w};
#pragma unroll
      for (int i = 0; i < 4; i++)
#pragma unroll
        for (int j = 0; j < 4; j++)
          acc[i][j] = fmaf(a_[i], b_[j], acc[i][j]);
    }
    __syncthreads();
  }
#pragma unroll
  for (int i = 0; i < 4; i++) {
    int m = m0 + (ty << 2) + i;
    if (m >= S_) continue;
#pragma unroll
    for (int j = 0; j < 4; j++) {
      int n = n0 + (tx << 2) + j;
      if (n < S_) Cm[(long)m * S_ + n] = acc[i][j] * 0.125f;
    }
  }
}

__global__ __launch_bounds__(256) void softmax_rows(float* __restrict__ sc)
{
  int row = blockIdx.x * 4 + (threadIdx.x >> 6);
  int lane = threadIdx.x & 63;
  float* p = sc + (long)row * S_;
  float v[5]; float mx = -3.0e38f;
#pragma unroll
  for (int j = 0; j < 5; j++) {
    int idx = lane + (j << 6);
    v[j] = (idx < S_) ? p[idx] : -3.0e38f;
    mx = fmaxf(mx, v[j]);
  }
  mx = warp_rmax(mx);
  float sum = 0.f;
#pragma unroll
  for (int j = 0; j < 5; j++) {
    int idx = lane + (j << 6);
    float e = (idx < S_) ? expf(v[j] - mx) : 0.f;
    v[j] = e; sum += e;
  }
  sum = warp_rsum(sum);
  float inv = 1.0f / sum;
#pragma unroll
  for (int j = 0; j < 5; j++) {
    int idx = lane + (j << 6);
    if (idx < S_) p[idx] = v[j] * inv;
  }
}

// P@V for the chunk -> ctx split f16 hi/lo [CH][512]
__global__ __launch_bounds__(256) void spatial_pv(
    const float* __restrict__ qkvc, const float* __restrict__ scores,
    ushort* __restrict__ ctxH, ushort* __restrict__ ctxL, int fh_base)
{
  const int fh = fh_base + blockIdx.z;
  const int fl = fh >> 3, hh = fh & 7;
  const float* P = scores + (long)blockIdx.z * S_ * S_;
  const float* V = qkvc + (long)fl * S_ * 1536 + 1024 + hh * HD_;
  const int m0 = blockIdx.x << 6;
  __shared__ __align__(16) float Ps[16][68];
  __shared__ __align__(16) float Vs[16][64];
  const int tid = threadIdx.x, tx = tid & 15, ty = tid >> 4;
  const int lr = tid >> 2, lc = (tid & 3) << 2;
  const int br = tid >> 4, bc = (tid & 15) << 2;
  float acc[4][4] = {};
  for (int k0 = 0; k0 < S_; k0 += 16) {
#pragma unroll
    for (int e = 0; e < 4; e++) {
      int kcol = k0 + lc + e;
      Ps[lc+e][lr] = (m0 + lr < S_ && kcol < S_) ? P[(long)(m0 + lr) * S_ + kcol] : 0.f;
    }
    int vrr = k0 + br;
    float4 vv = make_float4(0,0,0,0);
    if (vrr < S_) vv = *(const float4*)(V + (long)vrr * 1536 + bc);
    *(float4*)&Vs[br][bc] = vv;
    __syncthreads();
#pragma unroll
    for (int kk = 0; kk < 16; kk++) {
      const float4 a4 = *(const float4*)&Ps[kk][ty << 2];
      const float4 b4 = *(const float4*)&Vs[kk][tx << 2];
      const float a_[4] = {a4.x, a4.y, a4.z, a4.w};
      const float b_[4] = {b4.x, b4.y, b4.z, b4.w};
#pragma unroll
      for (int i = 0; i < 4; i++)
#pragma unroll
        for (int j = 0; j < 4; j++)
          acc[i][j] = fmaf(a_[i], b_[j], acc[i][j]);
    }
    __syncthreads();
  }
#pragma unroll
  for (int i = 0; i < 4; i++) {
    int m = m0 + (ty << 2) + i;
    if (m >= S_) continue;
#pragma unroll
    for (int j = 0; j < 4; j++) {
      int n = (tx << 2) + j;
      long o = ((long)fl * S_ + m) * D_ + hh * HD_ + n;
      ushort h, l;
      split_f16(acc[i][j], h, l);
      ctxH[o] = h; ctxL[o] = l;
    }
  }
}

// ---------------- temporal causal attention for one batch chunk (rows t*257+s), split-out
__global__ __launch_bounds__(64) void temporal_attn(
    const float* __restrict__ qkvc, ushort* __restrict__ ctxH, ushort* __restrict__ ctxL)
{
  const int gid = blockIdx.x;           // s*8+h
  const int hh = gid & 7;
  const int s = gid >> 3;
  const int lane = threadIdx.x;
  __shared__ float Qs[16][65];
  __shared__ float Ks[16][65];
  __shared__ float Pm[16][17];
  float v[16];
  const long base = (long)s * 1536 + hh * HD_ + lane;
  const long tstr = (long)S_ * 1536;
#pragma unroll
  for (int t = 0; t < 16; t++) {
    long r = base + t * tstr;
    Qs[t][lane] = qkvc[r];
    Ks[t][lane] = qkvc[r + 512];
    v[t] = qkvc[r + 1024];
  }
  __syncthreads();
  const int rq = lane >> 2, c0 = lane & 3;
  float sc[4];
#pragma unroll
  for (int j = 0; j < 4; j++) {
    int c = c0 + (j << 2);
    if (c <= rq) {
      float d = 0.f;
#pragma unroll
      for (int k = 0; k < 64; k++) d = fmaf(Qs[rq][k], Ks[c][k], d);
      sc[j] = d * 0.125f;
    } else sc[j] = -3.0e38f;
  }
  float mx = fmaxf(fmaxf(sc[0], sc[1]), fmaxf(sc[2], sc[3]));
  mx = fmaxf(mx, __shfl_xor(mx, 1));
  mx = fmaxf(mx, __shfl_xor(mx, 2));
  float sum = 0.f;
#pragma unroll
  for (int j = 0; j < 4; j++) { sc[j] = expf(sc[j] - mx); sum += sc[j]; }
  sum += __shfl_xor(sum, 1);
  sum += __shfl_xor(sum, 2);
  float inv = 1.0f / sum;
#pragma unroll
  for (int j = 0; j < 4; j++) Pm[rq][c0 + (j << 2)] = sc[j] * inv;
  __syncthreads();
#pragma unroll
  for (int t = 0; t < 16; t++) {
    float o = 0.f;
#pragma unroll
    for (int k = 0; k < 16; k++) o = fmaf(Pm[t][k], v[k], o);
    long idx = ((long)t * S_ + s) * D_ + hh * HD_ + lane;
    ushort h, l;
    split_f16(o, h, l);
    ctxH[idx] = h; ctxL[idx] = l;
  }
}

// ---------------- final LN + projection + VQ argmin + action head
__global__ __launch_bounds__(256) void final_vq(
    const float* __restrict__ tok, const float* __restrict__ lnf_g,
    const float* __restrict__ lnf_b, const float* __restrict__ out_w,
    const float* __restrict__ codebook, const float* __restrict__ action_w,
    float* __restrict__ out)
{
  __shared__ float xs[512];
  __shared__ float red[256];
  __shared__ float zs[64];
  __shared__ float bd[256];
  __shared__ int   bi[256];
  const int b = blockIdx.x / 15, tm = blockIdx.x % 15;
  const int tid = threadIdx.x;
  const float* xr = tok + ((long)(b * T_ + tm + 1) * S_) * D_;   // s = 0
  xs[tid] = xr[tid]; xs[tid + 256] = xr[tid + 256];
  red[tid] = xs[tid] + xs[tid + 256];
  __syncthreads();
  for (int off = 128; off >= 1; off >>= 1) {
    if (tid < off) red[tid] += red[tid + off];
    __syncthreads();
  }
  float mean = red[0] * (1.0f / 512.0f);
  __syncthreads();
  float d0 = xs[tid] - mean, d1 = xs[tid + 256] - mean;
  red[tid] = d0 * d0 + d1 * d1;
  __syncthreads();
  for (int off = 128; off >= 1; off >>= 1) {
    if (tid < off) red[tid] += red[tid + off];
    __syncthreads();
  }
  float rs = rsqrtf(red[0] * (1.0f / 512.0f) + 1e-5f);
  __syncthreads();
  xs[tid]       = d0 * rs * lnf_g[tid]       + lnf_b[tid];
  xs[tid + 256] = d1 * rs * lnf_g[tid + 256] + lnf_b[tid + 256];
  __syncthreads();
  if (tid < 64) {
    float z = 0.f;
    for (int d = 0; d < 512; d++) z = fmaf(xs[d], out_w[d * 64 + tid], z);
    zs[tid] = z;
  }
  __syncthreads();
  float best = 3.0e38f; int bidx = 0;
  for (int c = tid; c < 4096; c += 256) {
    const float* cp = codebook + (long)c * 64;
    float dot = 0.f, cn = 0.f;
#pragma unroll 8
    for (int k = 0; k < 64; k++) { float w = cp[k]; dot = fmaf(zs[k], w, dot); cn = fmaf(w, w, cn); }
    float dist = cn - 2.0f * dot;
    if (dist < best) { best = dist; bidx = c; }
  }
  bd[tid] = best; bi[tid] = bidx;
  __syncthreads();
  for (int off = 128; off >= 1; off >>= 1) {
    if (tid < off) {
      if (bd[tid + off] < bd[tid] || (bd[tid + off] == bd[tid] && bi[tid + off] < bi[tid])) {
        bd[tid] = bd[tid + off]; bi[tid] = bi[tid + off];
      }
    }
    __syncthreads();
  }
  int idx = bi[0];
  if (tid < 16) {
    const float* cp = codebook + (long)idx * 64;
    float o = 0.f;
#pragma unroll
    for (int k = 0; k < 64; k++) o = fmaf(cp[k], action_w[k * 16 + tid], o);
    out[((long)(b * 15 + tm)) * 16 + tid] = o;
  }
}

extern "C" void kernel_launch(void* const* d_in, const int* in_sizes, int n_in,
                              void* d_out, int out_size, void* d_ws, size_t ws_size,
                              hipStream_t stream)
{
  const float* videos       = (const float*)d_in[0];
  const float* patch_w      = (const float*)d_in[1];
  const float* patch_b      = (const float*)d_in[2];
  const float* action_token = (const float*)d_in[3];
  const float* ln1_g  = (const float*)d_in[4];
  const float* ln1_b  = (const float*)d_in[5];
  const float* wqkv_s = (const float*)d_in[6];
  const float* wo_s   = (const float*)d_in[7];
  const float* ln2_g  = (const float*)d_in[8];
  const float* ln2_b  = (const float*)d_in[9];
  const float* wqkv_t = (const float*)d_in[10];
  const float* wo_t   = (const float*)d_in[11];
  const float* ln3_g  = (const float*)d_in[12];
  const float* ln3_b  = (const float*)d_in[13];
  const float* mlp_w1 = (const float*)d_in[14];
  const float* mlp_b1 = (const float*)d_in[15];
  const float* mlp_w2 = (const float*)d_in[16];
  const float* mlp_b2 = (const float*)d_in[17];
  const float* lnf_g  = (const float*)d_in[18];
  const float* lnf_b  = (const float*)d_in[19];
  const float* out_w  = (const float*)d_in[20];
  const float* codebook = (const float*)d_in[21];
  const float* action_w = (const float*)d_in[22];
  float* out = (float*)d_out;

  // ---- workspace layout (floats), total 33,693,760 = 134.77 MB (< proven 135.04)
  float* ws    = (float*)d_ws;
  float* tok   = ws;                                  // 16,842,752
  ushort* wt1h = (ushort*)(ws + 16842752);            // 1,048,576 f-equiv (hi+lo)
  ushort* wt1l = wt1h + 1048576;
  ushort* wt2h = (ushort*)(ws + 17891328);            // 1,048,576 f-equiv
  ushort* wt2l = wt2h + 1048576;
  float* qkvc  = ws + 18939904;                       // 6,316,032  (4112 x 1536)
  ushort* aH   = (ushort*)(ws + 25255936);            // 2,105,344 f-equiv (hi+lo, CH x 512)
  ushort* aL   = aH + 2105344;
  ushort* ctxH = (ushort*)(ws + 27361280);            // 2,105,344 f-equiv (hi+lo, CH x 512)
  ushort* ctxL = ctxH + 2105344;
  float* scratch = ws + 29466624;                     // 4,227,136  (scores 64 fh)
  ushort* midH = ctxH;                                // mid hi/lo (MCH x 2048) aliases ctx+scratch
  ushort* midL = midH + (long)MCH * FFN_;             // 6,291,456 f-equiv total <= 6,332,480

  // ---- patchify fused into embed GEMM; patch_w [192][512] -> wt1
  convert_w<<<dim3(3, 8), 256, 0, stream>>>(patch_w, wt1h, wt1l, 512, 192);
  gemm_mfma<128,4,4,1,true,false,false,false><<<dim3(257, 4), 256, 0, stream>>>(
      nullptr, nullptr, 0, wt1h, wt1l, 192, patch_b, tok, nullptr, nullptr,
      videos, action_token, NTOK, 512, 192);

  for (int L = 0; L < 4; L++) {
    // ================= spatial attention =================
    convert_w<<<dim3(8, 24), 256, 0, stream>>>(wqkv_s + (long)L*512*1536, wt1h, wt1l, 1536, 512);
    convert_w<<<dim3(8, 8),  256, 0, stream>>>(wo_s   + (long)L*512*512,  wt2h, wt2l, 512, 512);
    for (int cb = 0; cb < 8; cb++) {
      long r0 = (long)cb * CH;
      ln_split<<<CH / 4, 256, 0, stream>>>(tok + r0 * D_, ln1_g + L*512, ln1_b + L*512, aH, aL);
      gemm_mfma<128,4,4,0,false,false,false,false><<<dim3(33, 12), 256, 0, stream>>>(
          aH, aL, 512, wt1h, wt1l, 512, nullptr, qkvc, nullptr, nullptr,
          nullptr, nullptr, CH, 1536, 512);
      for (int hf = 0; hf < 2; hf++) {
        spatial_scores<<<dim3(5, 5, 64), 256, 0, stream>>>(qkvc, scratch, hf * 64);
        softmax_rows<<<(64 * S_) / 4, 256, 0, stream>>>(scratch);
        spatial_pv<<<dim3(5, 1, 64), 256, 0, stream>>>(qkvc, scratch, ctxH, ctxL, hf * 64);
      }
      gemm_mfma<64,2,4,0,false,false,true,false><<<dim3(33, 8), 256, 0, stream>>>(
          ctxH, ctxL, 512, wt2h, wt2l, 512, nullptr, tok + r0 * D_, nullptr, nullptr,
          nullptr, nullptr, CH, 512, 512);
    }
    // ================= temporal attention =================
    convert_w<<<dim3(8, 24), 256, 0, stream>>>(wqkv_t + (long)L*512*1536, wt1h, wt1l, 1536, 512);
    convert_w<<<dim3(8, 8),  256, 0, stream>>>(wo_t   + (long)L*512*512,  wt2h, wt2l, 512, 512);
    for (int b = 0; b < 8; b++) {
      long r0 = (long)b * CH;
      ln_split<<<CH / 4, 256, 0, stream>>>(tok + r0 * D_, ln2_g + L*512, ln2_b + L*512, aH, aL);
      gemm_mfma<128,4,4,0,false,false,false,false><<<dim3(33, 12), 256, 0, stream>>>(
          aH, aL, 512, wt1h, wt1l, 512, nullptr, qkvc, nullptr, nullptr,
          nullptr, nullptr, CH, 1536, 512);
      temporal_attn<<<S_ * NH_, 64, 0, stream>>>(qkvc, ctxH, ctxL);
      gemm_mfma<64,2,4,0,false,false,true,false><<<dim3(33, 8), 256, 0, stream>>>(
          ctxH, ctxL, 512, wt2h, wt2l, 512, nullptr, tok + r0 * D_, nullptr, nullptr,
          nullptr, nullptr, CH, 512, 512);
    }
    // ================= MLP (M-chunks of 3072 rows; W1 writes split mid) =================
    convert_w<<<dim3(8, 32), 256, 0, stream>>>(mlp_w1 + (long)L*512*2048, wt1h, wt1l, 2048, 512);
    convert_w<<<dim3(32, 8), 256, 0, stream>>>(mlp_w2 + (long)L*2048*512, wt2h, wt2l, 512, 2048);
    for (int c = 0; c < 11; c++) {
      long m0r = (long)c * MCH;
      int mr = NTOK - (int)m0r; if (mr > MCH) mr = MCH;
      if (mr <= 0) break;
      ln_split<<<mr / 4, 256, 0, stream>>>(tok + m0r * D_, ln3_g + L*512, ln3_b + L*512, aH, aL);
      gemm_mfma<128,4,4,0,true,true,false,true><<<dim3((mr + 127) / 128, 16), 256, 0, stream>>>(
          aH, aL, 512, wt1h, wt1l, 512, mlp_b1 + (long)L*2048, nullptr, midH, midL,
          nullptr, nullptr, mr, FFN_, 512);
      gemm_mfma<64,2,4,0,true,false,true,false><<<dim3((mr + 127) / 128, 8), 256, 0, stream>>>(
          midH, midL, 2048, wt2h, wt2l, 2048, mlp_b2 + (long)L*512, tok + m0r * D_,
          nullptr, nullptr, nullptr, nullptr, mr, 512, 2048);
    }
  }

  final_vq<<<B_ * (T_ - 1), 256, 0, stream>>>(tok, lnf_g, lnf_b, out_w, codebook, action_w, out);
}

// Round 7
// 10107.430 us; speedup vs baseline: 1.4598x; 1.4598x over previous
//
#include <hip/hip_runtime.h>
#include <hip/hip_bf16.h>

#define B_ 8
#define T_ 16
#define S_ 257
#define D_ 512
#define FFN_ 2048
#define NH_ 8
#define HD_ 64
#define PTD_ 192
#define NTOK (B_*T_*S_)        // 32896
#define CH 4112                // 16 frames * 257 rows per chunk
#define MCH 4096               // MLP row chunk
#define WSCALE 64.0f
#define WINV 0.015625f

typedef unsigned int uint;
typedef unsigned short ushort;
typedef __attribute__((ext_vector_type(8))) _Float16 half8;
typedef __attribute__((ext_vector_type(4))) float f32x4;

__device__ __forceinline__ float warp_rsum(float v){
#pragma unroll
  for (int m = 32; m >= 1; m >>= 1) v += __shfl_xor(v, m);
  return v;
}
__device__ __forceinline__ float gelu_f(float x){
  float x3 = x*x*x;
  return 0.5f*x*(1.0f + tanhf(0.7978845608028654f*(x + 0.044715f*x3)));
}
// split fp32 -> f16 hi + f16 lo (RNE).
__device__ __forceinline__ void split_f16(float f, ushort& h, ushort& l){
  _Float16 hh = (_Float16)f;
  float hf = (float)hh;
  _Float16 ll = (_Float16)(f - hf);
  h = __builtin_bit_cast(ushort, hh);
  l = __builtin_bit_cast(ushort, ll);
}

// ---------------- fused LN + f16-split:  aH/aL[row][512] = split(LN(x[row]))
__global__ __launch_bounds__(256) void ln_split(
    const float* __restrict__ x, const float* __restrict__ g,
    const float* __restrict__ bb, ushort* __restrict__ aH, ushort* __restrict__ aL)
{
  int row = blockIdx.x * 4 + (threadIdx.x >> 6);
  int lane = threadIdx.x & 63;
  const float* xr = x + (long)row * D_;
  float4 u0 = *(const float4*)(xr + lane * 8);
  float4 u1 = *(const float4*)(xr + lane * 8 + 4);
  float s = u0.x + u0.y + u0.z + u0.w + u1.x + u1.y + u1.z + u1.w;
  s = warp_rsum(s);
  float mean = s * (1.0f / 512.0f);
  float d[8] = {u0.x - mean, u0.y - mean, u0.z - mean, u0.w - mean,
                u1.x - mean, u1.y - mean, u1.z - mean, u1.w - mean};
  float ss = 0.f;
#pragma unroll
  for (int i = 0; i < 8; i++) ss = fmaf(d[i], d[i], ss);
  ss = warp_rsum(ss);
  float rstd = rsqrtf(ss * (1.0f / 512.0f) + 1e-5f);
  int c = lane * 8;
  float4 g0 = *(const float4*)(g + c), g1 = *(const float4*)(g + c + 4);
  float4 b0 = *(const float4*)(bb + c), b1 = *(const float4*)(bb + c + 4);
  float y[8] = {d[0]*rstd*g0.x + b0.x, d[1]*rstd*g0.y + b0.y,
                d[2]*rstd*g0.z + b0.z, d[3]*rstd*g0.w + b0.w,
                d[4]*rstd*g1.x + b1.x, d[5]*rstd*g1.y + b1.y,
                d[6]*rstd*g1.z + b1.z, d[7]*rstd*g1.w + b1.w};
  ushort h[8], l[8];
#pragma unroll
  for (int i = 0; i < 8; i++) split_f16(y[i], h[i], l[i]);
  uint4 hv = make_uint4((uint)h[0] | ((uint)h[1] << 16), (uint)h[2] | ((uint)h[3] << 16),
                        (uint)h[4] | ((uint)h[5] << 16), (uint)h[6] | ((uint)h[7] << 16));
  uint4 lv = make_uint4((uint)l[0] | ((uint)l[1] << 16), (uint)l[2] | ((uint)l[3] << 16),
                        (uint)l[4] | ((uint)l[5] << 16), (uint)l[6] | ((uint)l[7] << 16));
  *(uint4*)(aH + (long)row * 512 + c) = hv;
  *(uint4*)(aL + (long)row * 512 + c) = lv;
}

// ---------------- weight transpose + split:  W[K][N] f32 -> (W*64) as Whi[N][K], Wlo[N][K] f16
__global__ __launch_bounds__(256) void convert_w(
    const float* __restrict__ W, ushort* __restrict__ Whi, ushort* __restrict__ Wlo,
    int N, int K)
{
  __shared__ float Tt[64][65];
  const int tid = threadIdx.x;
  const int k0 = blockIdx.x << 6, n0 = blockIdx.y << 6;
  {
    int kk = tid >> 2, nb = (tid & 3) << 4;
#pragma unroll
    for (int q = 0; q < 4; q++) {
      float4 v = *(const float4*)(W + (long)(k0 + kk) * N + n0 + nb + 4 * q);
      Tt[kk][nb + 4*q + 0] = v.x; Tt[kk][nb + 4*q + 1] = v.y;
      Tt[kk][nb + 4*q + 2] = v.z; Tt[kk][nb + 4*q + 3] = v.w;
    }
  }
  __syncthreads();
  {
    int nn = tid >> 2, kb = (tid & 3) << 4;
    uint hw[8], lw[8];
#pragma unroll
    for (int q = 0; q < 8; q++) {
      float a = Tt[kb + 2*q][nn] * WSCALE, b = Tt[kb + 2*q + 1][nn] * WSCALE;
      ushort ha, la, hb, lb;
      split_f16(a, ha, la); split_f16(b, hb, lb);
      hw[q] = (uint)ha | ((uint)hb << 16); lw[q] = (uint)la | ((uint)lb << 16);
    }
    ushort* dh = Whi + (long)(n0 + nn) * K + k0 + kb;
    ushort* dl = Wlo + (long)(n0 + nn) * K + k0 + kb;
    ((uint4*)dh)[0] = make_uint4(hw[0], hw[1], hw[2], hw[3]);
    ((uint4*)dh)[1] = make_uint4(hw[4], hw[5], hw[6], hw[7]);
    ((uint4*)dl)[0] = make_uint4(lw[0], lw[1], lw[2], lw[3]);
    ((uint4*)dl)[1] = make_uint4(lw[4], lw[5], lw[6], lw[7]);
  }
}

// ---------------- split-f16 MFMA GEMM.  A pre-split (AMODE=0) or fused-patchify (AMODE=1).
template<int BN, int TM, int TN, int AMODE, bool BIAS, bool GELU, bool RESID, bool SOUT>
__global__ __launch_bounds__(256) void gemm_mfma(
    const ushort* __restrict__ aHp, const ushort* __restrict__ aLp, int lda,
    const ushort* __restrict__ wtH, const ushort* __restrict__ wtL, int ldb,
    const float* __restrict__ bias, float* __restrict__ C,
    ushort* __restrict__ coH, ushort* __restrict__ coL,
    const float* __restrict__ videos, const float* __restrict__ atok,
    int M, int N, int K)
{
  constexpr int NWC = BN / (TN * 16);
  __shared__ __align__(16) ushort sAh[128 * 40];
  __shared__ __align__(16) ushort sAl[128 * 40];
  __shared__ __align__(16) ushort sBh[BN * 40];
  __shared__ __align__(16) ushort sBl[BN * 40];
  const int tid = threadIdx.x;
  const int m0 = blockIdx.x * 128, n0 = blockIdx.y * BN;
  const int wid = tid >> 6, lane = tid & 63;
  const int lrow = lane & 15, lkg = lane >> 4;
  const int wr = wid / NWC, wc = wid % NWC;
  const int wrb = wr * TM * 16, wcb = wc * TN * 16;
  f32x4 acc[TM][TN];
#pragma unroll
  for (int mi = 0; mi < TM; mi++)
#pragma unroll
    for (int ni = 0; ni < TN; ni++) acc[mi][ni] = (f32x4){0.f, 0.f, 0.f, 0.f};

  const int rowa = tid >> 1, kba = (tid & 1) << 4;
  const int arow = m0 + rowa;
  const bool rowok = (arow < M);
  int bt_p = 0, s_p = 0;
  if (AMODE == 1) { bt_p = arow / 257; s_p = arow - bt_p * 257; }

  for (int k0 = 0; k0 < K; k0 += 32) {
    if (AMODE == 0) {
      uint4 h0 = make_uint4(0,0,0,0), h1 = h0, l0 = h0, l1 = h0;
      if (rowok) {
        const uint4* sh = (const uint4*)(aHp + (long)arow * lda + k0 + kba);
        const uint4* sl = (const uint4*)(aLp + (long)arow * lda + k0 + kba);
        h0 = sh[0]; h1 = sh[1]; l0 = sl[0]; l1 = sl[1];
      }
      uint4* dh = (uint4*)&sAh[rowa * 40 + kba];
      dh[0] = h0; dh[1] = h1;
      uint4* dl = (uint4*)&sAl[rowa * 40 + kba];
      dl[0] = l0; dl[1] = l1;
    } else {
      float4 vr[4];
#pragma unroll
      for (int q = 0; q < 4; q++) vr[q] = make_float4(0.f, 0.f, 0.f, 0.f);
#pragma unroll
      for (int q = 0; q < 4; q++) {
        int e4 = k0 + kba + 4 * q;
        if (s_p == 0) {
          vr[q] = *(const float4*)(atok + e4);
        } else {
          int p = s_p - 1, ph = p >> 4, pw = p & 15;
          int iq = e4 / 24, jc = e4 - iq * 24;
          vr[q] = *(const float4*)(videos + (long)bt_p * 49152 +
                                   (long)(ph * 8 + iq) * 384 + pw * 24 + jc);
        }
      }
      uint hw[8], lw[8];
#pragma unroll
      for (int q = 0; q < 4; q++) {
        ushort h0,l0,h1,l1,h2,l2,h3,l3;
        split_f16(vr[q].x, h0, l0); split_f16(vr[q].y, h1, l1);
        split_f16(vr[q].z, h2, l2); split_f16(vr[q].w, h3, l3);
        hw[2*q]   = (uint)h0 | ((uint)h1 << 16); lw[2*q]   = (uint)l0 | ((uint)l1 << 16);
        hw[2*q+1] = (uint)h2 | ((uint)h3 << 16); lw[2*q+1] = (uint)l2 | ((uint)l3 << 16);
      }
      uint4* dh = (uint4*)&sAh[rowa * 40 + kba];
      dh[0] = make_uint4(hw[0], hw[1], hw[2], hw[3]);
      dh[1] = make_uint4(hw[4], hw[5], hw[6], hw[7]);
      uint4* dl = (uint4*)&sAl[rowa * 40 + kba];
      dl[0] = make_uint4(lw[0], lw[1], lw[2], lw[3]);
      dl[1] = make_uint4(lw[4], lw[5], lw[6], lw[7]);
    }
    if (BN == 128) {
      const int colb = tid >> 1, kbb = (tid & 1) << 4;
      const ushort* srch = wtH + (long)(n0 + colb) * ldb + k0 + kbb;
      const ushort* srcl = wtL + (long)(n0 + colb) * ldb + k0 + kbb;
      uint4* dh = (uint4*)&sBh[colb * 40 + kbb];
      dh[0] = ((const uint4*)srch)[0]; dh[1] = ((const uint4*)srch)[1];
      uint4* dl = (uint4*)&sBl[colb * 40 + kbb];
      dl[0] = ((const uint4*)srcl)[0]; dl[1] = ((const uint4*)srcl)[1];
    } else {
      const int colb = tid >> 2, kbb = (tid & 3) << 3;
      *(uint4*)&sBh[colb * 40 + kbb] = *(const uint4*)(wtH + (long)(n0 + colb) * ldb + k0 + kbb);
      *(uint4*)&sBl[colb * 40 + kbb] = *(const uint4*)(wtL + (long)(n0 + colb) * ldb + k0 + kbb);
    }
    __syncthreads();
    half8 aH[TM], aL[TM];
#pragma unroll
    for (int mi = 0; mi < TM; mi++) {
      int off = (wrb + mi * 16 + lrow) * 40 + lkg * 8;
      aH[mi] = *(const half8*)&sAh[off];
      aL[mi] = *(const half8*)&sAl[off];
    }
#pragma unroll
    for (int ni = 0; ni < TN; ni++) {
      int off = (wcb + ni * 16 + lrow) * 40 + lkg * 8;
      half8 bH = *(const half8*)&sBh[off];
      half8 bL = *(const half8*)&sBl[off];
#pragma unroll
      for (int mi = 0; mi < TM; mi++) {
        acc[mi][ni] = __builtin_amdgcn_mfma_f32_16x16x32_f16(aL[mi], bH, acc[mi][ni], 0, 0, 0);
        acc[mi][ni] = __builtin_amdgcn_mfma_f32_16x16x32_f16(aH[mi], bL, acc[mi][ni], 0, 0, 0);
        acc[mi][ni] = __builtin_amdgcn_mfma_f32_16x16x32_f16(aH[mi], bH, acc[mi][ni], 0, 0, 0);
      }
    }
    __syncthreads();
  }
#pragma unroll
  for (int mi = 0; mi < TM; mi++) {
    int rowg = m0 + wrb + mi * 16 + lkg * 4;
#pragma unroll
    for (int j = 0; j < 4; j++) {
      int r = rowg + j;
      if (r < M) {
#pragma unroll
        for (int ni = 0; ni < TN; ni++) {
          int cg = n0 + wcb + ni * 16 + lrow;
          float v = acc[mi][ni][j] * WINV;
          if (BIAS) v += bias[cg];
          if (GELU) v = gelu_f(v);
          long idx = (long)r * N + cg;
          if (SOUT) {
            ushort h, l;
            split_f16(v, h, l);
            coH[idx] = h; coL[idx] = l;
          } else {
            if (RESID) C[idx] += v; else C[idx] = v;
          }
        }
      }
    }
  }
}

// ---------------- fused flash spatial attention (split-f16 MFMA, exact 2-pass softmax)
// grid (5 q-tiles, 128 fh).  Writes ctx split f16.
__global__ __launch_bounds__(256) void flash_spatial(
    const float* __restrict__ qkvc, ushort* __restrict__ ctxH, ushort* __restrict__ ctxL)
{
  __shared__ __align__(16) ushort sQh[64*72], sQl[64*72];
  __shared__ __align__(16) ushort sKh[64*72], sKl[64*72];
  __shared__ __align__(16) ushort sVh[64*72], sVl[64*72];   // V^T: [d][k]
  __shared__ __align__(16) ushort sPh[64*72], sPl[64*72];
  const int tid = threadIdx.x;
  const int wid = tid >> 6, lane = tid & 63;
  const int lr = lane & 15, lg = lane >> 4;
  const int fh = blockIdx.y;
  const int fl = fh >> 3, hh = fh & 7;
  const int q0 = blockIdx.x * 64;
  const float* Qb = qkvc + (long)fl * S_ * 1536 + hh * HD_;
  const float* Kb = Qb + 512;
  const float* Vb = Qb + 1024;
  const int srow = tid >> 2, sc0 = (tid & 3) << 4;

  // ---- stage Q (rows q0..q0+63), row-major split
  {
    int gr = q0 + srow;
    float4 v[4];
#pragma unroll
    for (int q = 0; q < 4; q++) v[q] = make_float4(0.f,0.f,0.f,0.f);
    if (gr < S_) {
#pragma unroll
      for (int q = 0; q < 4; q++) v[q] = *(const float4*)(Qb + (long)gr*1536 + sc0 + 4*q);
    }
    uint hw[8], lw[8];
#pragma unroll
    for (int q = 0; q < 4; q++) {
      ushort h0,l0,h1,l1,h2,l2,h3,l3;
      split_f16(v[q].x,h0,l0); split_f16(v[q].y,h1,l1);
      split_f16(v[q].z,h2,l2); split_f16(v[q].w,h3,l3);
      hw[2*q]   = (uint)h0 | ((uint)h1<<16); lw[2*q]   = (uint)l0 | ((uint)l1<<16);
      hw[2*q+1] = (uint)h2 | ((uint)h3<<16); lw[2*q+1] = (uint)l2 | ((uint)l3<<16);
    }
    uint4* dh = (uint4*)&sQh[srow*72 + sc0];
    dh[0] = make_uint4(hw[0],hw[1],hw[2],hw[3]);
    dh[1] = make_uint4(hw[4],hw[5],hw[6],hw[7]);
    uint4* dl = (uint4*)&sQl[srow*72 + sc0];
    dl[0] = make_uint4(lw[0],lw[1],lw[2],lw[3]);
    dl[1] = make_uint4(lw[4],lw[5],lw[6],lw[7]);
  }
  __syncthreads();
  // hoist Q fragments (wave's 16 q-rows)
  half8 qH[2], qL[2];
  {
    int qrl = wid * 16 + lr;
#pragma unroll
    for (int s = 0; s < 2; s++) {
      qH[s] = *(const half8*)&sQh[qrl*72 + s*32 + lg*8];
      qL[s] = *(const half8*)&sQl[qrl*72 + s*32 + lg*8];
    }
  }
  f32x4 accS[5][4];
#pragma unroll
  for (int t = 0; t < 5; t++)
#pragma unroll
    for (int kc = 0; kc < 4; kc++) accS[t][kc] = (f32x4){0.f,0.f,0.f,0.f};

  // ---- phase A: S = Q K^T over 5 k-tiles
#pragma unroll
  for (int t = 0; t < 5; t++) {
    __syncthreads();
    {
      int gr = t*64 + srow;
      float4 v[4];
#pragma unroll
      for (int q = 0; q < 4; q++) v[q] = make_float4(0.f,0.f,0.f,0.f);
      if (gr < S_) {
#pragma unroll
        for (int q = 0; q < 4; q++) v[q] = *(const float4*)(Kb + (long)gr*1536 + sc0 + 4*q);
      }
      uint hw[8], lw[8];
#pragma unroll
      for (int q = 0; q < 4; q++) {
        ushort h0,l0,h1,l1,h2,l2,h3,l3;
        split_f16(v[q].x,h0,l0); split_f16(v[q].y,h1,l1);
        split_f16(v[q].z,h2,l2); split_f16(v[q].w,h3,l3);
        hw[2*q]   = (uint)h0 | ((uint)h1<<16); lw[2*q]   = (uint)l0 | ((uint)l1<<16);
        hw[2*q+1] = (uint)h2 | ((uint)h3<<16); lw[2*q+1] = (uint)l2 | ((uint)l3<<16);
      }
      uint4* dh = (uint4*)&sKh[srow*72 + sc0];
      dh[0] = make_uint4(hw[0],hw[1],hw[2],hw[3]);
      dh[1] = make_uint4(hw[4],hw[5],hw[6],hw[7]);
      uint4* dl = (uint4*)&sKl[srow*72 + sc0];
      dl[0] = make_uint4(lw[0],lw[1],lw[2],lw[3]);
      dl[1] = make_uint4(lw[4],lw[5],lw[6],lw[7]);
    }
    __syncthreads();
#pragma unroll
    for (int s = 0; s < 2; s++) {
#pragma unroll
      for (int kc = 0; kc < 4; kc++) {
        int off = (kc*16 + lr)*72 + s*32 + lg*8;
        half8 bH = *(const half8*)&sKh[off];
        half8 bL = *(const half8*)&sKl[off];
        accS[t][kc] = __builtin_amdgcn_mfma_f32_16x16x32_f16(qL[s], bH, accS[t][kc], 0,0,0);
        accS[t][kc] = __builtin_amdgcn_mfma_f32_16x16x32_f16(qH[s], bL, accS[t][kc], 0,0,0);
        accS[t][kc] = __builtin_amdgcn_mfma_f32_16x16x32_f16(qH[s], bH, accS[t][kc], 0,0,0);
      }
    }
  }

  // ---- exact softmax over registers (row r = lg*4+j within wave; cols spread over lr)
  float m[4] = {-3.0e38f, -3.0e38f, -3.0e38f, -3.0e38f};
#pragma unroll
  for (int t = 0; t < 5; t++)
#pragma unroll
    for (int kc = 0; kc < 4; kc++) {
      int kcol = t*64 + kc*16 + lr;
      if (kcol < S_) {
#pragma unroll
        for (int j = 0; j < 4; j++) m[j] = fmaxf(m[j], accS[t][kc][j] * 0.125f);
      }
    }
#pragma unroll
  for (int mk = 8; mk >= 1; mk >>= 1)
#pragma unroll
    for (int j = 0; j < 4; j++) m[j] = fmaxf(m[j], __shfl_xor(m[j], mk));
  float l[4] = {0.f, 0.f, 0.f, 0.f};
#pragma unroll
  for (int t = 0; t < 5; t++)
#pragma unroll
    for (int kc = 0; kc < 4; kc++) {
      int kcol = t*64 + kc*16 + lr;
#pragma unroll
      for (int j = 0; j < 4; j++) {
        float p = (kcol < S_) ? expf(accS[t][kc][j]*0.125f - m[j]) : 0.f;
        accS[t][kc][j] = p;
        l[j] += p;
      }
    }
#pragma unroll
  for (int mk = 8; mk >= 1; mk >>= 1)
#pragma unroll
    for (int j = 0; j < 4; j++) l[j] += __shfl_xor(l[j], mk);

  // ---- phase B: O = P V over 5 k-tiles
  f32x4 accO[4];
#pragma unroll
  for (int dc = 0; dc < 4; dc++) accO[dc] = (f32x4){0.f,0.f,0.f,0.f};
#pragma unroll
  for (int t = 0; t < 5; t++) {
    // write P_t to wave-private LDS rows (C-layout -> row-major)
#pragma unroll
    for (int kc = 0; kc < 4; kc++)
#pragma unroll
      for (int j = 0; j < 4; j++) {
        ushort h, lo2;
        split_f16(accS[t][kc][j], h, lo2);
        int addr = (wid*16 + lg*4 + j)*72 + kc*16 + lr;
        sPh[addr] = h; sPl[addr] = lo2;
      }
    __syncthreads();
    // stage V^T tile: sV[d][k] = V[k][d]
    {
      int gr = t*64 + srow;
      float4 v[4];
#pragma unroll
      for (int q = 0; q < 4; q++) v[q] = make_float4(0.f,0.f,0.f,0.f);
      if (gr < S_) {
#pragma unroll
        for (int q = 0; q < 4; q++) v[q] = *(const float4*)(Vb + (long)gr*1536 + sc0 + 4*q);
      }
#pragma unroll
      for (int q = 0; q < 4; q++) {
        float vals[4] = {v[q].x, v[q].y, v[q].z, v[q].w};
#pragma unroll
        for (int e = 0; e < 4; e++) {
          ushort h, lo2;
          split_f16(vals[e], h, lo2);
          int d = sc0 + 4*q + e;
          sVh[d*72 + srow] = h; sVl[d*72 + srow] = lo2;
        }
      }
    }
    __syncthreads();
#pragma unroll
    for (int s = 0; s < 2; s++) {
      int poff = (wid*16 + lr)*72 + s*32 + lg*8;
      half8 pH = *(const half8*)&sPh[poff];
      half8 pL = *(const half8*)&sPl[poff];
#pragma unroll
      for (int dc = 0; dc < 4; dc++) {
        int voff = (dc*16 + lr)*72 + s*32 + lg*8;
        half8 vH = *(const half8*)&sVh[voff];
        half8 vL = *(const half8*)&sVl[voff];
        accO[dc] = __builtin_amdgcn_mfma_f32_16x16x32_f16(pL, vH, accO[dc], 0,0,0);
        accO[dc] = __builtin_amdgcn_mfma_f32_16x16x32_f16(pH, vL, accO[dc], 0,0,0);
        accO[dc] = __builtin_amdgcn_mfma_f32_16x16x32_f16(pH, vH, accO[dc], 0,0,0);
      }
    }
  }
  // ---- epilogue: O/l -> ctx split
#pragma unroll
  for (int j = 0; j < 4; j++) {
    int grow = q0 + wid*16 + lg*4 + j;
    if (grow < S_) {
      float inv = 1.0f / l[j];
#pragma unroll
      for (int dc = 0; dc < 4; dc++) {
        float o = accO[dc][j] * inv;
        ushort h, lo2;
        split_f16(o, h, lo2);
        long idx = ((long)fl * S_ + grow) * 512 + hh*64 + dc*16 + lr;
        ctxH[idx] = h; ctxL[idx] = lo2;
      }
    }
  }
}

// ---------------- temporal causal attention for one batch chunk (rows t*257+s), split-out
__global__ __launch_bounds__(64) void temporal_attn(
    const float* __restrict__ qkvc, ushort* __restrict__ ctxH, ushort* __restrict__ ctxL)
{
  const int gid = blockIdx.x;           // s*8+h
  const int hh = gid & 7;
  const int s = gid >> 3;
  const int lane = threadIdx.x;
  __shared__ float Qs[16][65];
  __shared__ float Ks[16][65];
  __shared__ float Pm[16][17];
  float v[16];
  const long base = (long)s * 1536 + hh * HD_ + lane;
  const long tstr = (long)S_ * 1536;
#pragma unroll
  for (int t = 0; t < 16; t++) {
    long r = base + t * tstr;
    Qs[t][lane] = qkvc[r];
    Ks[t][lane] = qkvc[r + 512];
    v[t] = qkvc[r + 1024];
  }
  __syncthreads();
  const int rq = lane >> 2, c0 = lane & 3;
  float sc[4];
#pragma unroll
  for (int j = 0; j < 4; j++) {
    int c = c0 + (j << 2);
    if (c <= rq) {
      float d = 0.f;
#pragma unroll
      for (int k = 0; k < 64; k++) d = fmaf(Qs[rq][k], Ks[c][k], d);
      sc[j] = d * 0.125f;
    } else sc[j] = -3.0e38f;
  }
  float mx = fmaxf(fmaxf(sc[0], sc[1]), fmaxf(sc[2], sc[3]));
  mx = fmaxf(mx, __shfl_xor(mx, 1));
  mx = fmaxf(mx, __shfl_xor(mx, 2));
  float sum = 0.f;
#pragma unroll
  for (int j = 0; j < 4; j++) { sc[j] = expf(sc[j] - mx); sum += sc[j]; }
  sum += __shfl_xor(sum, 1);
  sum += __shfl_xor(sum, 2);
  float inv = 1.0f / sum;
#pragma unroll
  for (int j = 0; j < 4; j++) Pm[rq][c0 + (j << 2)] = sc[j] * inv;
  __syncthreads();
#pragma unroll
  for (int t = 0; t < 16; t++) {
    float o = 0.f;
#pragma unroll
    for (int k = 0; k < 16; k++) o = fmaf(Pm[t][k], v[k], o);
    long idx = ((long)t * S_ + s) * D_ + hh * HD_ + lane;
    ushort h, l;
    split_f16(o, h, l);
    ctxH[idx] = h; ctxL[idx] = l;
  }
}

// ---------------- final LN + projection + VQ argmin + action head
__global__ __launch_bounds__(256) void final_vq(
    const float* __restrict__ tok, const float* __restrict__ lnf_g,
    const float* __restrict__ lnf_b, const float* __restrict__ out_w,
    const float* __restrict__ codebook, const float* __restrict__ action_w,
    float* __restrict__ out)
{
  __shared__ float xs[512];
  __shared__ float red[256];
  __shared__ float zs[64];
  __shared__ float bd[256];
  __shared__ int   bi[256];
  const int b = blockIdx.x / 15, tm = blockIdx.x % 15;
  const int tid = threadIdx.x;
  const float* xr = tok + ((long)(b * T_ + tm + 1) * S_) * D_;   // s = 0
  xs[tid] = xr[tid]; xs[tid + 256] = xr[tid + 256];
  red[tid] = xs[tid] + xs[tid + 256];
  __syncthreads();
  for (int off = 128; off >= 1; off >>= 1) {
    if (tid < off) red[tid] += red[tid + off];
    __syncthreads();
  }
  float mean = red[0] * (1.0f / 512.0f);
  __syncthreads();
  float d0 = xs[tid] - mean, d1 = xs[tid + 256] - mean;
  red[tid] = d0 * d0 + d1 * d1;
  __syncthreads();
  for (int off = 128; off >= 1; off >>= 1) {
    if (tid < off) red[tid] += red[tid + off];
    __syncthreads();
  }
  float rs = rsqrtf(red[0] * (1.0f / 512.0f) + 1e-5f);
  __syncthreads();
  xs[tid]       = d0 * rs * lnf_g[tid]       + lnf_b[tid];
  xs[tid + 256] = d1 * rs * lnf_g[tid + 256] + lnf_b[tid + 256];
  __syncthreads();
  if (tid < 64) {
    float z = 0.f;
    for (int d = 0; d < 512; d++) z = fmaf(xs[d], out_w[d * 64 + tid], z);
    zs[tid] = z;
  }
  __syncthreads();
  float best = 3.0e38f; int bidx = 0;
  for (int c = tid; c < 4096; c += 256) {
    const float* cp = codebook + (long)c * 64;
    float dot = 0.f, cn = 0.f;
#pragma unroll 8
    for (int k = 0; k < 64; k++) { float w = cp[k]; dot = fmaf(zs[k], w, dot); cn = fmaf(w, w, cn); }
    float dist = cn - 2.0f * dot;
    if (dist < best) { best = dist; bidx = c; }
  }
  bd[tid] = best; bi[tid] = bidx;
  __syncthreads();
  for (int off = 128; off >= 1; off >>= 1) {
    if (tid < off) {
      if (bd[tid + off] < bd[tid] || (bd[tid + off] == bd[tid] && bi[tid + off] < bi[tid])) {
        bd[tid] = bd[tid + off]; bi[tid] = bi[tid + off];
      }
    }
    __syncthreads();
  }
  int idx = bi[0];
  if (tid < 16) {
    const float* cp = codebook + (long)idx * 64;
    float o = 0.f;
#pragma unroll
    for (int k = 0; k < 64; k++) o = fmaf(cp[k], action_w[k * 16 + tid], o);
    out[((long)(b * 15 + tm)) * 16 + tid] = o;
  }
}

extern "C" void kernel_launch(void* const* d_in, const int* in_sizes, int n_in,
                              void* d_out, int out_size, void* d_ws, size_t ws_size,
                              hipStream_t stream)
{
  const float* videos       = (const float*)d_in[0];
  const float* patch_w      = (const float*)d_in[1];
  const float* patch_b      = (const float*)d_in[2];
  const float* action_token = (const float*)d_in[3];
  const float* ln1_g  = (const float*)d_in[4];
  const float* ln1_b  = (const float*)d_in[5];
  const float* wqkv_s = (const float*)d_in[6];
  const float* wo_s   = (const float*)d_in[7];
  const float* ln2_g  = (const float*)d_in[8];
  const float* ln2_b  = (const float*)d_in[9];
  const float* wqkv_t = (const float*)d_in[10];
  const float* wo_t   = (const float*)d_in[11];
  const float* ln3_g  = (const float*)d_in[12];
  const float* ln3_b  = (const float*)d_in[13];
  const float* mlp_w1 = (const float*)d_in[14];
  const float* mlp_b1 = (const float*)d_in[15];
  const float* mlp_w2 = (const float*)d_in[16];
  const float* mlp_b2 = (const float*)d_in[17];
  const float* lnf_g  = (const float*)d_in[18];
  const float* lnf_b  = (const float*)d_in[19];
  const float* out_w  = (const float*)d_in[20];
  const float* codebook = (const float*)d_in[21];
  const float* action_w = (const float*)d_in[22];
  float* out = (float*)d_out;

  // ---- workspace layout (floats), total 31,571,968 f = 126.29 MB (< proven 135)
  float* ws    = (float*)d_ws;
  float* tok   = ws;                                  // 16,842,752
  ushort* wt1h = (ushort*)(ws + 16842752);            // 1,048,576 f-equiv (hi+lo)
  ushort* wt1l = wt1h + 1048576;
  ushort* wt2h = (ushort*)(ws + 17891328);            // 1,048,576 f-equiv
  ushort* wt2l = wt2h + 1048576;
  ushort* aH   = (ushort*)(ws + 18939904);            // 2,105,344 f-equiv (CH x 512 hi+lo)
  ushort* aL   = aH + 2105344;
  float* qkvc  = ws + 21045248;                       // 6,316,032 f (4112 x 1536)
  ushort* ctxH = (ushort*)(ws + 27361280);            // 4,210,688 f-equiv (2*CH x 512 hi+lo)
  ushort* ctxL = ctxH + 4210688;
  ushort* midH = (ushort*)(ws + 21045248);            // MLP mid (MCH x 2048), aliases qkvc+ctx
  ushort* midL = midH + (long)MCH * FFN_;

  // ---- patchify fused into embed GEMM
  convert_w<<<dim3(3, 8), 256, 0, stream>>>(patch_w, wt1h, wt1l, 512, 192);
  gemm_mfma<128,4,4,1,true,false,false,false><<<dim3(257, 4), 256, 0, stream>>>(
      nullptr, nullptr, 0, wt1h, wt1l, 192, patch_b, tok, nullptr, nullptr,
      videos, action_token, NTOK, 512, 192);

  for (int L = 0; L < 4; L++) {
    // ================= spatial attention =================
    convert_w<<<dim3(8, 24), 256, 0, stream>>>(wqkv_s + (long)L*512*1536, wt1h, wt1l, 1536, 512);
    convert_w<<<dim3(8, 8),  256, 0, stream>>>(wo_s   + (long)L*512*512,  wt2h, wt2l, 512, 512);
    for (int pr = 0; pr < 4; pr++) {
      for (int ci = 0; ci < 2; ci++) {
        long r0 = (long)(2 * pr + ci) * CH;
        ln_split<<<CH / 4, 256, 0, stream>>>(tok + r0 * D_, ln1_g + L*512, ln1_b + L*512, aH, aL);
        gemm_mfma<128,4,4,0,false,false,false,false><<<dim3(33, 12), 256, 0, stream>>>(
            aH, aL, 512, wt1h, wt1l, 512, nullptr, qkvc, nullptr, nullptr,
            nullptr, nullptr, CH, 1536, 512);
        flash_spatial<<<dim3(5, 128), 256, 0, stream>>>(
            qkvc, ctxH + (long)ci * CH * D_, ctxL + (long)ci * CH * D_);
      }
      gemm_mfma<64,2,4,0,false,false,true,false><<<dim3(65, 8), 256, 0, stream>>>(
          ctxH, ctxL, 512, wt2h, wt2l, 512, nullptr, tok + (long)pr * 2 * CH * D_,
          nullptr, nullptr, nullptr, nullptr, 2 * CH, 512, 512);
    }
    // ================= temporal attention =================
    convert_w<<<dim3(8, 24), 256, 0, stream>>>(wqkv_t + (long)L*512*1536, wt1h, wt1l, 1536, 512);
    convert_w<<<dim3(8, 8),  256, 0, stream>>>(wo_t   + (long)L*512*512,  wt2h, wt2l, 512, 512);
    for (int pr = 0; pr < 4; pr++) {
      for (int ci = 0; ci < 2; ci++) {
        long r0 = (long)(2 * pr + ci) * CH;
        ln_split<<<CH / 4, 256, 0, stream>>>(tok + r0 * D_, ln2_g + L*512, ln2_b + L*512, aH, aL);
        gemm_mfma<128,4,4,0,false,false,false,false><<<dim3(33, 12), 256, 0, stream>>>(
            aH, aL, 512, wt1h, wt1l, 512, nullptr, qkvc, nullptr, nullptr,
            nullptr, nullptr, CH, 1536, 512);
        temporal_attn<<<S_ * NH_, 64, 0, stream>>>(
            qkvc, ctxH + (long)ci * CH * D_, ctxL + (long)ci * CH * D_);
      }
      gemm_mfma<64,2,4,0,false,false,true,false><<<dim3(65, 8), 256, 0, stream>>>(
          ctxH, ctxL, 512, wt2h, wt2l, 512, nullptr, tok + (long)pr * 2 * CH * D_,
          nullptr, nullptr, nullptr, nullptr, 2 * CH, 512, 512);
    }
    // ================= MLP (M-chunks of 4096 rows) =================
    convert_w<<<dim3(8, 32), 256, 0, stream>>>(mlp_w1 + (long)L*512*2048, wt1h, wt1l, 2048, 512);
    convert_w<<<dim3(32, 8), 256, 0, stream>>>(mlp_w2 + (long)L*2048*512, wt2h, wt2l, 512, 2048);
    for (int c = 0; c < 9; c++) {
      long m0r = (long)c * MCH;
      int mr = NTOK - (int)m0r; if (mr > MCH) mr = MCH;
      if (mr <= 0) break;
      ln_split<<<mr / 4, 256, 0, stream>>>(tok + m0r * D_, ln3_g + L*512, ln3_b + L*512, aH, aL);
      gemm_mfma<128,4,4,0,true,true,false,true><<<dim3((mr + 127) / 128, 16), 256, 0, stream>>>(
          aH, aL, 512, wt1h, wt1l, 512, mlp_b1 + (long)L*2048, nullptr, midH, midL,
          nullptr, nullptr, mr, FFN_, 512);
      gemm_mfma<64,2,4,0,true,false,true,false><<<dim3((mr + 127) / 128, 8), 256, 0, stream>>>(
          midH, midL, 2048, wt2h, wt2l, 2048, mlp_b2 + (long)L*512, tok + m0r * D_,
          nullptr, nullptr, nullptr, nullptr, mr, 512, 2048);
    }
  }

  final_vq<<<B_ * (T_ - 1), 256, 0, stream>>>(tok, lnf_g, lnf_b, out_w, codebook, action_w, out);
}